// Round 5
// baseline (383.358 us; speedup 1.0000x reference)
//
#include <hip/hip_runtime.h>
#include <hip/hip_bf16.h>

#define S_LEN 512
#define HDIM 1024
#define H2 2048

typedef float f32x4 __attribute__((ext_vector_type(4)));
typedef float f32x2 __attribute__((ext_vector_type(2)));
typedef __bf16 bf16x8 __attribute__((ext_vector_type(8)));

// ---------------- K1: e1[b,h] = hidden[b,:] . Wa[h,0:1024] + ba[h]  (f32 exact)
#define E1_PITCH 258
__global__ __launch_bounds__(256) void k_e1(const float* __restrict__ hidden,
                                            const float* __restrict__ Wa,
                                            const float* __restrict__ ba,
                                            float* __restrict__ e1) {
    __shared__ float hsh[64 * E1_PITCH];
    int h = blockIdx.x * 4 + (threadIdx.x >> 6);
    int lane = threadIdx.x & 63;
    const float* wrow = Wa + (size_t)h * H2;  // hidden-half of Wa row
    float acc = 0.f;
    for (int k0 = 0; k0 < HDIM; k0 += 256) {
        __syncthreads();
        for (int idx = threadIdx.x; idx < 4096; idx += 256) {
            int b = idx >> 6, ck = (idx & 63) << 2;
            f32x4 v = *(const f32x4*)(hidden + b * HDIM + k0 + ck);
            f32x2 lo; lo[0] = v[0]; lo[1] = v[1];
            f32x2 hi; hi[0] = v[2]; hi[1] = v[3];
            *(f32x2*)(hsh + b * E1_PITCH + ck) = lo;
            *(f32x2*)(hsh + b * E1_PITCH + ck + 2) = hi;
        }
        __syncthreads();
        const float* wr = wrow + k0;
        const float* hb = hsh + lane * E1_PITCH;
#pragma unroll 8
        for (int kk = 0; kk < 256; kk += 4) {
            f32x4 w = *(const f32x4*)(wr + kk);
            f32x2 h01 = *(const f32x2*)(hb + kk);
            f32x2 h23 = *(const f32x2*)(hb + kk + 2);
            acc += w[0] * h01[0] + w[1] * h01[1] + w[2] * h23[0] + w[3] * h23[1];
        }
    }
    e1[lane * HDIM + h] = acc + ba[h];
}

// ---------------- K2: pack Wa2 (f32) -> bf16 BK=64 tiles (gload_lds order) + zero
// Tile (nt,kt): 128 rows x 8 slots of 16B. LDS chunk (row,sl) holds source cols
// ((sl ^ (row&7)) * 8 .. +8) of k-tile kt. Linear chunk order = gload_lds order.
__global__ __launch_bounds__(256) void k_packB(const float* __restrict__ Wa,
                                               unsigned short* __restrict__ wsB,
                                               float* __restrict__ logits) {
    int ci = blockIdx.x * 256 + threadIdx.x;      // 16B chunk id, 0..131071
    if (ci < S_LEN * 64) logits[ci] = 0.f;        // fused zero (32768 floats)
    int tile = ci >> 10;                          // 128 tiles = nt*16 + kt
    int wi = ci & 1023;
    int row = wi >> 3;
    int slot = wi & 7;
    int nt = tile >> 4, kt = tile & 15;
    int n = nt * 128 + row;
    int kk = kt * 64 + ((slot ^ (row & 7)) << 3);
    const float* src = Wa + (size_t)n * H2 + HDIM + kk;  // encoder half
    f32x4 a = *(const f32x4*)src;
    f32x4 b = *(const f32x4*)(src + 4);
    bf16x8 o;
    o[0] = (__bf16)a[0]; o[1] = (__bf16)a[1]; o[2] = (__bf16)a[2]; o[3] = (__bf16)a[3];
    o[4] = (__bf16)b[0]; o[5] = (__bf16)b[1]; o[6] = (__bf16)b[2]; o[7] = (__bf16)b[3];
    *(bf16x8*)(wsB + (size_t)ci * 8) = o;
}

// ---------------- K3: fused GEMM (enc->bf16 @ Wa2^T) + relu + Ws-dot -> atomics
// 128x128 tile, BK=64, SINGLE 32KB LDS buffer, 2 barriers per K-tile (16 tiles).
// B: 4x global_load_lds from packed wsB, drained by counted vmcnt(8).
// A: f32 reg-prefetch (tile t+1 issued at tile t) -> cvt -> swizzled ds_write.
__global__ __launch_bounds__(256) void k_main(const float* __restrict__ enc,
                                              const unsigned short* __restrict__ wsB,
                                              const float* __restrict__ e1,
                                              const float* __restrict__ Ws,
                                              float* __restrict__ logits) {
    __shared__ __align__(16) unsigned short As[8192];  // [128][64] bf16, XOR-swizzled
    __shared__ __align__(16) unsigned short Bs[8192];

    int i = blockIdx.x;
    // XCD-aware: the 8 n-blocks sharing an A-panel land on one XCD.
    int mt = ((i >> 6) << 3) | (i & 7);
    int nt = (i >> 3) & 7;
    int r0 = mt * 128;
    int n0 = nt * 128;

    int tid = threadIdx.x;
    int lane = tid & 63, wid = tid >> 6;
    int wr = wid >> 1, wc = wid & 1;
    int c = lane & 15, g = lane >> 4;

    // A staging: thread owns chunks (row0 + it*32, slotA), it=0..3; 16B each.
    int row0 = tid >> 3;
    int slotA = tid & 7;
    int colBase = ((slotA ^ (row0 & 7)) << 3);   // row&7 invariant under +32
    const float* abase = enc + (size_t)(r0 + row0) * HDIM + colBase;

    f32x4 acc[4][4] = {};
    f32x4 p[8], q[8];

    // ---- prologue: A(0) -> p regs
#pragma unroll
    for (int it = 0; it < 4; ++it) {
        const float* ap = abase + (size_t)it * 32 * HDIM;
        p[2 * it]     = *(const f32x4*)(ap);
        p[2 * it + 1] = *(const f32x4*)(ap + 4);
    }

#pragma unroll 2
    for (int t = 0; t < 16; ++t) {
        // --- B(t): 4x global_load_lds (issued FIRST; drained by vmcnt(8))
        const unsigned short* bsrc = wsB + ((size_t)(nt * 16 + t) << 13);
#pragma unroll
        for (int it = 0; it < 4; ++it) {
            __builtin_amdgcn_global_load_lds(
                (const __attribute__((address_space(1))) void*)(bsrc + (size_t)(tid + it * 256) * 8),
                (__attribute__((address_space(3))) void*)((char*)Bs + it * 4096 + wid * 1024),
                16, 0, 0);
        }
        __builtin_amdgcn_sched_barrier(0);

        // --- A(t+1) f32 loads (in flight across barriers + MFMA)
        {
            int tn = (t < 15) ? t + 1 : 15;
            const float* an = abase + tn * 64;
#pragma unroll
            for (int it = 0; it < 4; ++it) {
                const float* ap = an + (size_t)it * 32 * HDIM;
                q[2 * it]     = *(const f32x4*)(ap);
                q[2 * it + 1] = *(const f32x4*)(ap + 4);
            }
        }
        __builtin_amdgcn_sched_barrier(0);

        // --- cvt A(t) (loaded one tile ago) -> swizzled ds_write_b128 x4
#pragma unroll
        for (int it = 0; it < 4; ++it) {
            bf16x8 o;
            f32x4 lo = p[2 * it], hi = p[2 * it + 1];
            o[0] = (__bf16)lo[0]; o[1] = (__bf16)lo[1]; o[2] = (__bf16)lo[2]; o[3] = (__bf16)lo[3];
            o[4] = (__bf16)hi[0]; o[5] = (__bf16)hi[1]; o[6] = (__bf16)hi[2]; o[7] = (__bf16)hi[3];
            *(bf16x8*)((char*)As + (size_t)(tid + it * 256) * 16) = o;
        }

        // barrier1: drain the 4 B gload_lds (A(t+1)'s 8 stay in flight) + ds_writes
        asm volatile("s_waitcnt vmcnt(8) lgkmcnt(0)" ::: "memory");
        __builtin_amdgcn_sched_barrier(0);
        __builtin_amdgcn_s_barrier();
        __builtin_amdgcn_sched_barrier(0);

        // --- fragments + MFMA, per k-slice (ks = 0,1)
#pragma unroll
        for (int ks = 0; ks < 2; ++ks) {
            bf16x8 af[4], bfr[4];
#pragma unroll
            for (int m = 0; m < 4; ++m) {
                int row = wr * 64 + m * 16 + c;
                int sl = (ks * 4 + g) ^ (row & 7);
                af[m] = *(const bf16x8*)((const char*)As + row * 128 + sl * 16);
            }
#pragma unroll
            for (int n = 0; n < 4; ++n) {
                int rowb = wc * 64 + n * 16 + c;
                int sl = (ks * 4 + g) ^ (rowb & 7);
                bfr[n] = *(const bf16x8*)((const char*)Bs + rowb * 128 + sl * 16);
            }
            __builtin_amdgcn_s_setprio(1);
#pragma unroll
            for (int m = 0; m < 4; ++m)
#pragma unroll
                for (int n = 0; n < 4; ++n)
                    acc[m][n] = __builtin_amdgcn_mfma_f32_16x16x32_bf16(af[m], bfr[n], acc[m][n], 0, 0, 0);
            __builtin_amdgcn_s_setprio(0);
        }

        // barrier2: all LDS reads retired before next tile overwrites the buffer
        __builtin_amdgcn_sched_barrier(0);
        __builtin_amdgcn_s_barrier();
        __builtin_amdgcn_sched_barrier(0);

#pragma unroll
        for (int r = 0; r < 8; ++r) p[r] = q[r];
    }

    // --- epilogue: v = relu(acc + e1[b,h]); partial = v . Ws; atomicAdd
    float wsv[4];
#pragma unroll
    for (int n = 0; n < 4; ++n) wsv[n] = Ws[n0 + wc * 64 + n * 16 + c];

#pragma unroll
    for (int m = 0; m < 4; ++m) {
#pragma unroll
        for (int j = 0; j < 4; ++j) {
            int rl = wr * 64 + m * 16 + g * 4 + j;
            int r = r0 + rl;
            int b = r & 63, sidx = r >> 6;
            const float* e1b = e1 + b * HDIM + n0 + wc * 64;
            float pp = 0.f;
#pragma unroll
            for (int n = 0; n < 4; ++n) {
                float v = acc[m][n][j] + e1b[n * 16 + c];
                v = fmaxf(v, 0.f);
                pp += v * wsv[n];
            }
            pp += __shfl_xor(pp, 1);
            pp += __shfl_xor(pp, 2);
            pp += __shfl_xor(pp, 4);
            pp += __shfl_xor(pp, 8);
            if (c == 0) atomicAdd(&logits[b * S_LEN + sidx], pp);
        }
    }
}

// ---------------- K4: logits -> softmax probs, in place on d_out ----------------
__global__ __launch_bounds__(512) void k_softmax(float* __restrict__ out,
                                                 const float* __restrict__ pe,
                                                 const int* __restrict__ mask,
                                                 float scale) {
    __shared__ float red[8];
    int b = blockIdx.x, s = threadIdx.x;
    int idx = (b << 9) + s;
    float acc = out[idx];
    float logit = (mask[idx] != 0) ? -1e12f : (scale * acc + pe[idx]);
    float m = logit;
#pragma unroll
    for (int o = 32; o >= 1; o >>= 1) m = fmaxf(m, __shfl_xor(m, o));
    if ((s & 63) == 0) red[s >> 6] = m;
    __syncthreads();
    float m2 = red[0];
#pragma unroll
    for (int i2 = 1; i2 < 8; ++i2) m2 = fmaxf(m2, red[i2]);
    float e = expf(logit - m2);
    float t = e;
#pragma unroll
    for (int o = 32; o >= 1; o >>= 1) t += __shfl_xor(t, o);
    __syncthreads();
    if ((s & 63) == 0) red[s >> 6] = t;
    __syncthreads();
    float tot = 0.f;
#pragma unroll
    for (int i2 = 0; i2 < 8; ++i2) tot += red[i2];
    out[idx] = e / tot;
}

extern "C" void kernel_launch(void* const* d_in, const int* in_sizes, int n_in,
                              void* d_out, int out_size, void* d_ws, size_t ws_size,
                              hipStream_t stream) {
    const float* hidden = (const float*)d_in[0];
    const float* enc    = (const float*)d_in[1];
    const float* pe     = (const float*)d_in[2];
    const int*   mask   = (const int*)d_in[3];
    const float* Wa     = (const float*)d_in[4];
    const float* ba     = (const float*)d_in[5];
    const float* Ws     = (const float*)d_in[6];
    float* out = (float*)d_out;

    float* e1 = (float*)d_ws;                                       // 256 KB
    unsigned short* wsB = (unsigned short*)((char*)d_ws + 262144);  // 2 MB

    const float scale = 0.19494764453248462f;  // log(512)/sqrt(1024)

    k_e1<<<256, 256, 0, stream>>>(hidden, Wa, ba, e1);
    k_packB<<<512, 256, 0, stream>>>(Wa, wsB, out);
    k_main<<<2048, 256, 0, stream>>>(enc, wsB, e1, Ws, out);
    k_softmax<<<64, 512, 0, stream>>>(out, pe, mask, scale);
}

// Round 6
// 355.729 us; speedup vs baseline: 1.0777x; 1.0777x over previous
//
#include <hip/hip_runtime.h>
#include <hip/hip_bf16.h>

#define S_LEN 512
#define HDIM 1024
#define H2 2048

typedef float f32x4 __attribute__((ext_vector_type(4)));
typedef float f32x2 __attribute__((ext_vector_type(2)));
typedef __bf16 bf16x8 __attribute__((ext_vector_type(8)));

// ---------------- K1: e1[b,h] = hidden[b,:] . Wa[h,0:1024] + ba[h]  (f32 exact)
#define E1_PITCH 258
__global__ __launch_bounds__(256) void k_e1(const float* __restrict__ hidden,
                                            const float* __restrict__ Wa,
                                            const float* __restrict__ ba,
                                            float* __restrict__ e1) {
    __shared__ float hsh[64 * E1_PITCH];
    int h = blockIdx.x * 4 + (threadIdx.x >> 6);
    int lane = threadIdx.x & 63;
    const float* wrow = Wa + (size_t)h * H2;  // hidden-half of Wa row
    float acc = 0.f;
    for (int k0 = 0; k0 < HDIM; k0 += 256) {
        __syncthreads();
        for (int idx = threadIdx.x; idx < 4096; idx += 256) {
            int b = idx >> 6, ck = (idx & 63) << 2;
            f32x4 v = *(const f32x4*)(hidden + b * HDIM + k0 + ck);
            f32x2 lo; lo[0] = v[0]; lo[1] = v[1];
            f32x2 hi; hi[0] = v[2]; hi[1] = v[3];
            *(f32x2*)(hsh + b * E1_PITCH + ck) = lo;
            *(f32x2*)(hsh + b * E1_PITCH + ck + 2) = hi;
        }
        __syncthreads();
        const float* wr = wrow + k0;
        const float* hb = hsh + lane * E1_PITCH;
#pragma unroll 8
        for (int kk = 0; kk < 256; kk += 4) {
            f32x4 w = *(const f32x4*)(wr + kk);
            f32x2 h01 = *(const f32x2*)(hb + kk);
            f32x2 h23 = *(const f32x2*)(hb + kk + 2);
            acc += w[0] * h01[0] + w[1] * h01[1] + w[2] * h23[0] + w[3] * h23[1];
        }
    }
    e1[lane * HDIM + h] = acc + ba[h];
}

// ---------------- K2: pack Wa2 (f32) -> bf16 BK=32 tiles (round-2 layout) + zero
// Tile (nt,kt): 128 rows x 4 slots of 16B; chunk (row,slot) holds source cols
// ((slot ^ ((row>>1)&3)) * 8 ..). Linear chunk order = gload_lds dest order.
__global__ __launch_bounds__(256) void k_packB(const float* __restrict__ Wa,
                                               unsigned short* __restrict__ wsB,
                                               float* __restrict__ logits) {
    int ci = blockIdx.x * 256 + threadIdx.x;      // 16B chunk id, 0..131071
    if (ci < S_LEN * 64) logits[ci] = 0.f;        // fused zero (32768 floats)
    int tile = ci >> 9;
    int wi = ci & 511;
    int row = wi >> 2;
    int slot = wi & 3;
    int nt = tile >> 5, kt = tile & 31;
    int n = nt * 128 + row;
    int kk = kt * 32 + ((slot ^ ((row >> 1) & 3)) << 3);
    const float* src = Wa + (size_t)n * H2 + HDIM + kk;  // encoder half
    f32x4 a = *(const f32x4*)src;
    f32x4 b = *(const f32x4*)(src + 4);
    bf16x8 o;
    o[0] = (__bf16)a[0]; o[1] = (__bf16)a[1]; o[2] = (__bf16)a[2]; o[3] = (__bf16)a[3];
    o[4] = (__bf16)b[0]; o[5] = (__bf16)b[1]; o[6] = (__bf16)b[2]; o[7] = (__bf16)b[3];
    *(bf16x8*)(wsB + (size_t)ci * 8) = o;
}

// ---------------- K3: fused GEMM + relu + Ws-dot -> atomic logits
// 128x128 tile, BK=32. A staged as F32 directly from enc via global_load_lds
// (source-side slot^ (row&7) swizzle, linear LDS dest); converted to bf16 at
// fragment load. B bf16 pre-packed. LDS double-buffered (A 2x16KB + B 2x8KB =
// 48KB -> 3 blocks/CU). Counted vmcnt(6): stage t+1 issued before draining t.
// No ds_writes -> no lgkmcnt drain at barrier 1.
__global__ __launch_bounds__(256, 3) void k_main(const float* __restrict__ enc,
                                                 const unsigned short* __restrict__ wsB,
                                                 const float* __restrict__ e1,
                                                 const float* __restrict__ Ws,
                                                 float* __restrict__ logits) {
    // [0,16K)+[16K,32K): A f32 [128][32], row pitch 128B, slots swizzled
    // [32K,40K)+[40K,48K): B bf16 [128][32], row pitch 64B, swizzled
    __shared__ __align__(16) char lds[49152];

    int i = blockIdx.x;
    // XCD-aware: the 8 n-blocks sharing an A-panel land on one XCD.
    int mt = ((i >> 6) << 3) | (i & 7);
    int nt = (i >> 3) & 7;
    int r0 = mt * 128;
    int n0 = nt * 128;

    int tid = threadIdx.x;
    int lane = tid & 63, wid = tid >> 6;
    int wr = wid >> 1, wc = wid & 1;
    int c = lane & 15, g = lane >> 4;

    // A stage source addressing: call it covers rows it*32 + (tid>>3), slot tid&7.
    int arow = tid >> 3;          // 0..31
    int aslot = tid & 7;
    int acol = (aslot ^ (arow & 7)) << 2;   // f32 col; (row&7)==(arow&7) for all it
    const float* asrc0 = enc + (size_t)(r0 + arow) * HDIM + acol;

    const unsigned short* bbase = wsB + ((size_t)(nt * 32) << 12);

    f32x4 acc[4][4] = {};

#define STAGE_AB(AOFF, BOFF, KT)                                                        \
    {                                                                                   \
        const float* as_ = asrc0 + (KT) * 32;                                           \
        _Pragma("unroll")                                                               \
        for (int it = 0; it < 4; ++it) {                                                \
            __builtin_amdgcn_global_load_lds(                                           \
                (const __attribute__((address_space(1))) void*)(as_ + (size_t)it * 32 * HDIM), \
                (__attribute__((address_space(3))) void*)(lds + (AOFF) + it * 4096 + wid * 1024), \
                16, 0, 0);                                                              \
        }                                                                               \
        const unsigned short* bs_ = bbase + ((size_t)(KT) << 12);                       \
        _Pragma("unroll")                                                               \
        for (int it = 0; it < 2; ++it) {                                                \
            __builtin_amdgcn_global_load_lds(                                           \
                (const __attribute__((address_space(1))) void*)(bs_ + (size_t)(tid + it * 256) * 8), \
                (__attribute__((address_space(3))) void*)(lds + (BOFF) + it * 4096 + wid * 1024), \
                16, 0, 0);                                                              \
        }                                                                               \
    }

    // prologue: tile 0 -> buf0
    STAGE_AB(0, 32768, 0);

#pragma unroll 2
    for (int t = 0; t < 32; ++t) {
        int ca = (t & 1) ? 16384 : 0;
        int na = ca ^ 16384;
        int cbb = (t & 1) ? 40960 : 32768;
        int nb = cbb ^ 8192;
        int tn = (t < 31) ? t + 1 : 31;   // t=31: dummy re-stage (keeps vmcnt uniform)

        STAGE_AB(na, nb, tn);
        __builtin_amdgcn_sched_barrier(0);
        // drain tile t's 6 loads (oldest); tile t+1's 6 stay in flight
        asm volatile("s_waitcnt vmcnt(6)" ::: "memory");
        __builtin_amdgcn_sched_barrier(0);
        __builtin_amdgcn_s_barrier();
        __builtin_amdgcn_sched_barrier(0);

        // --- A fragments: f32 LDS -> cvt bf16; B fragments: bf16 LDS
        bf16x8 af[4], bfr[4];
#pragma unroll
        for (int m = 0; m < 4; ++m) {
            int rowa = wr * 64 + m * 16 + c;
            const char* pa = lds + ca + rowa * 128;
            int s0 = (2 * g) ^ (rowa & 7);
            f32x4 fa = *(const f32x4*)(pa + s0 * 16);
            f32x4 fb = *(const f32x4*)(pa + (s0 ^ 1) * 16);
            bf16x8 o;
            o[0] = (__bf16)fa[0]; o[1] = (__bf16)fa[1]; o[2] = (__bf16)fa[2]; o[3] = (__bf16)fa[3];
            o[4] = (__bf16)fb[0]; o[5] = (__bf16)fb[1]; o[6] = (__bf16)fb[2]; o[7] = (__bf16)fb[3];
            af[m] = o;
        }
#pragma unroll
        for (int n = 0; n < 4; ++n) {
            int rowb = wc * 64 + n * 16 + c;
            int sl = g ^ ((rowb >> 1) & 3);
            bfr[n] = *(const bf16x8*)(lds + cbb + rowb * 64 + sl * 16);
        }
        __builtin_amdgcn_s_setprio(1);
#pragma unroll
        for (int m = 0; m < 4; ++m)
#pragma unroll
            for (int n = 0; n < 4; ++n)
                acc[m][n] = __builtin_amdgcn_mfma_f32_16x16x32_bf16(af[m], bfr[n], acc[m][n], 0, 0, 0);
        __builtin_amdgcn_s_setprio(0);

        // readers done -> next iter may overwrite this buffer
        __builtin_amdgcn_sched_barrier(0);
        __builtin_amdgcn_s_barrier();
        __builtin_amdgcn_sched_barrier(0);
    }
    // drain the dummy stage before epilogue / endpgm (LDS writes must land
    // while this block still owns the LDS)
    asm volatile("s_waitcnt vmcnt(0)" ::: "memory");

    // --- epilogue: v = relu(acc + e1[b,h]); p = v . Ws; atomicAdd into logits
    float wsv[4];
#pragma unroll
    for (int n = 0; n < 4; ++n) wsv[n] = Ws[n0 + wc * 64 + n * 16 + c];

#pragma unroll
    for (int m = 0; m < 4; ++m) {
#pragma unroll
        for (int j = 0; j < 4; ++j) {
            int rl = wr * 64 + m * 16 + g * 4 + j;
            int r = r0 + rl;
            int b = r & 63, sidx = r >> 6;
            const float* e1b = e1 + b * HDIM + n0 + wc * 64;
            float pp = 0.f;
#pragma unroll
            for (int n = 0; n < 4; ++n) {
                float v = acc[m][n][j] + e1b[n * 16 + c];
                v = fmaxf(v, 0.f);
                pp += v * wsv[n];
            }
            pp += __shfl_xor(pp, 1);
            pp += __shfl_xor(pp, 2);
            pp += __shfl_xor(pp, 4);
            pp += __shfl_xor(pp, 8);
            if (c == 0) atomicAdd(&logits[b * S_LEN + sidx], pp);
        }
    }
#undef STAGE_AB
}

// ---------------- K4: logits -> softmax probs, in place on d_out ----------------
__global__ __launch_bounds__(512) void k_softmax(float* __restrict__ out,
                                                 const float* __restrict__ pe,
                                                 const int* __restrict__ mask,
                                                 float scale) {
    __shared__ float red[8];
    int b = blockIdx.x, s = threadIdx.x;
    int idx = (b << 9) + s;
    float acc = out[idx];
    float logit = (mask[idx] != 0) ? -1e12f : (scale * acc + pe[idx]);
    float m = logit;
#pragma unroll
    for (int o = 32; o >= 1; o >>= 1) m = fmaxf(m, __shfl_xor(m, o));
    if ((s & 63) == 0) red[s >> 6] = m;
    __syncthreads();
    float m2 = red[0];
#pragma unroll
    for (int i2 = 1; i2 < 8; ++i2) m2 = fmaxf(m2, red[i2]);
    float e = expf(logit - m2);
    float t = e;
#pragma unroll
    for (int o = 32; o >= 1; o >>= 1) t += __shfl_xor(t, o);
    __syncthreads();
    if ((s & 63) == 0) red[s >> 6] = t;
    __syncthreads();
    float tot = 0.f;
#pragma unroll
    for (int i2 = 0; i2 < 8; ++i2) tot += red[i2];
    out[idx] = e / tot;
}

extern "C" void kernel_launch(void* const* d_in, const int* in_sizes, int n_in,
                              void* d_out, int out_size, void* d_ws, size_t ws_size,
                              hipStream_t stream) {
    const float* hidden = (const float*)d_in[0];
    const float* enc    = (const float*)d_in[1];
    const float* pe     = (const float*)d_in[2];
    const int*   mask   = (const int*)d_in[3];
    const float* Wa     = (const float*)d_in[4];
    const float* ba     = (const float*)d_in[5];
    const float* Ws     = (const float*)d_in[6];
    float* out = (float*)d_out;

    float* e1 = (float*)d_ws;                                       // 256 KB
    unsigned short* wsB = (unsigned short*)((char*)d_ws + 262144);  // 2 MB

    const float scale = 0.19494764453248462f;  // log(512)/sqrt(1024)

    k_e1<<<256, 256, 0, stream>>>(hidden, Wa, ba, e1);
    k_packB<<<512, 256, 0, stream>>>(Wa, wsB, out);
    k_main<<<2048, 256, 0, stream>>>(enc, wsB, e1, Ws, out);
    k_softmax<<<64, 512, 0, stream>>>(out, pe, mask, scale);
}